// Round 11
// baseline (67.554 us; speedup 1.0000x reference)
//
#include <hip/hip_runtime.h>
#include <cstdint>
#include <cstddef>

// Problem constants
#define B_    32
#define N_    5023
#define F_    64
#define S_    9
#define OUT_  128
#define M_TOT (B_ * N_)        // 160736
#define K_    (S_ * F_)        // 576

// Workspace layout (bytes)
#define X_ELEMS   (B_ * N_ * F_)          // 10,287,104
#define WS_XB     0                        // bf16 x: 20,574,208 B
#define WS_WB     20574208                 // bf16 W: 147,456 B

typedef __attribute__((ext_vector_type(8))) short          bf16x8;
typedef __attribute__((ext_vector_type(4))) float          f32x4;
typedef __attribute__((ext_vector_type(8))) unsigned short u16x8;

// ---------------------------------------------------------------------------
// Fused fp32->bf16 (RNE) conversion for x and W in one grid.
// ---------------------------------------------------------------------------
__global__ void cvt_xw(const float* __restrict__ x, const float* __restrict__ W,
                       unsigned short* __restrict__ xb, unsigned short* __restrict__ Wb,
                       int nx8, int nw8) {
    const int i = blockIdx.x * blockDim.x + threadIdx.x;
    const float* src;
    unsigned short* dst;
    if (i < nx8) { src = x + (size_t)i * 8; dst = xb + (size_t)i * 8; }
    else {
        const int j = i - nx8;
        if (j >= nw8) return;
        src = W + (size_t)j * 8; dst = Wb + (size_t)j * 8;
    }
    const float4 v0 = ((const float4*)src)[0], v1 = ((const float4*)src)[1];
    const float vv[8] = {v0.x, v0.y, v0.z, v0.w, v1.x, v1.y, v1.z, v1.w};
    u16x8 r;
    #pragma unroll
    for (int k = 0; k < 8; ++k) {
        uint32_t u = __float_as_uint(vv[k]);
        u = u + 0x7fffu + ((u >> 16) & 1u);
        r[k] = (unsigned short)(u >> 16);
    }
    *(u16x8*)dst = r;
}

// ---------------------------------------------------------------------------
// Round-11 main kernel: BARRIER-FREE main loop.
// Block: 256 rows x 128 cols (all cols -> 1x gather volume), 8 waves, each
// wave 32 rows x 128 cols (2 mi x 8 ni frags of mfma_f32_16x16x32_bf16).
//
// W: ENTIRE weight matrix resident in LDS (128x576 bf16 = 147,456 B),
//    loaded once per block with coalesced linear reads + ds_write_b128,
//    XOR-chunk-swizzled per row: phys16Bchunk = c ^ (o&7)  (rows 1152 B,
//    16-B aligned; makes B-frag reads 2-way max = free). ONE barrier total.
// A: gathered straight into registers by pinned inline-asm
//    global_load_dwordx4, ring-3 (named rA/rB/rC), counted vmcnt(8/4/0)
//    (+sched_barrier(0), rule #18). No other in-loop VMEM -> exact counts.
//    After the single barrier, waves free-run: no inter-wave coupling, so
//    random gather tail latency is absorbed per-wave by ring slack + TLP.
// ---------------------------------------------------------------------------
__global__ __launch_bounds__(512, 2)
void spiral_mfma(const unsigned short* __restrict__ xb,
                 const void* __restrict__ adj,
                 const unsigned short* __restrict__ Wb,
                 const float* __restrict__ bias,
                 float* __restrict__ out) {
    __shared__ unsigned short Wl[128 * 576];   // 147,456 B

    const int tid = threadIdx.x;
    const int l   = tid & 63;
    const int w   = tid >> 6;                  // 0..7
    const int r15 = l & 15;
    const int kc  = l >> 4;                    // 0..3
    const int e7  = l & 7;

    // Uniform dtype probe: odd 32-bit words of the first 8 int64 slots are
    // all zero iff adj is int64. Scalar loads, broadcast.
    const int* aw = (const int*)adj;
    const int pv = aw[1] | aw[3] | aw[5] | aw[7] | aw[9] | aw[11] | aw[13] | aw[15];
    const int sh = (pv == 0) ? 3 : 2;          // byte shift per element
    const char* adjp = (const char*)adj;

    // Bijective XCD-chunked swizzle for 628 blocks (628 = 8*78 + 4, m204):
    const int bid = blockIdx.x;
    const int xcd = bid & 7, li = bid >> 3;
    const int nb  = (xcd < 4 ? xcd * 79 : 316 + (xcd - 4) * 78) + li;
    const int m0  = nb * 256;
    const int wrow0 = m0 + w * 32;

    // Per-thread gather rows (2 mi x 16 rows via l&15) + all 9 indices.
    uint32_t xrb[2];
    int      idxv[2][S_];
    #pragma unroll
    for (int mi = 0; mi < 2; ++mi) {
        int m = wrow0 + mi * 16 + r15;
        if (m >= M_TOT) m = M_TOT - 1;
        xrb[mi] = (uint32_t)(m / N_) * (N_ * F_);
        const int base = m * S_;
        #pragma unroll
        for (int s = 0; s < S_; ++s)
            idxv[mi][s] = *(const int*)(adjp + ((size_t)(base + s) << sh));
    }

    // ---- W staging: coalesced linear reads, swizzled ds_write_b128 ----
    // cid = j*512 + tid covers all 9216 16-B chunks; src is fully linear.
    #pragma unroll
    for (int j = 0; j < 18; ++j) {
        const int cid = j * 512 + tid;
        const int o   = cid / 72;              // row (magic-mul)
        const int c   = cid - o * 72;          // logical chunk in row
        const u16x8 v = *(const u16x8*)(Wb + (size_t)cid * 8);
        *(u16x8*)&Wl[o * 576 + ((c ^ (o & 7)) << 3)] = v;
    }

    // ---- A ring-3: pinned inline-asm gathers ----
    bf16x8 rA[2][2], rB[2][2], rC[2][2];

    #define LOAD_A(BUF, sidx)                                                   \
        do {                                                                    \
            _Pragma("unroll")                                                   \
            for (int mi = 0; mi < 2; ++mi) {                                    \
                const unsigned short* p_ =                                      \
                    xb + xrb[mi] + (uint32_t)idxv[mi][(sidx)] * 64u + kc * 8;   \
                asm volatile("global_load_dwordx4 %0, %2, off\n\t"              \
                             "global_load_dwordx4 %1, %2, off offset:64"        \
                             : "=&v"(BUF[mi][0]), "=&v"(BUF[mi][1])             \
                             : "v"(p_)                                          \
                             : "memory");                                       \
            }                                                                   \
        } while (0)

    #define WAITA(N_)                                                           \
        do {                                                                    \
            asm volatile("s_waitcnt vmcnt(" #N_ ")" ::: "memory");              \
            __builtin_amdgcn_sched_barrier(0);                                  \
        } while (0)

    // One kstep = K=32 slice: 8 B-frag ds_reads + 16 MFMA.
    #define CK(ks_, BUF)                                                        \
        do {                                                                    \
            bf16x8 bv[8];                                                       \
            _Pragma("unroll")                                                   \
            for (int ni = 0; ni < 8; ++ni)                                      \
                bv[ni] = *(const bf16x8*)                                       \
                    &Wl[(ni * 16 + r15) * 576 + ((((ks_) * 4 + kc) ^ e7) << 3)];\
            __builtin_amdgcn_s_setprio(1);                                      \
            _Pragma("unroll")                                                   \
            for (int mi = 0; mi < 2; ++mi)                                      \
                _Pragma("unroll")                                               \
                for (int ni = 0; ni < 8; ++ni)                                  \
                    acc[mi][ni] = __builtin_amdgcn_mfma_f32_16x16x32_bf16(      \
                        BUF[mi][(ks_) & 1], bv[ni], acc[mi][ni], 0, 0, 0);      \
            __builtin_amdgcn_s_setprio(0);                                      \
        } while (0)

    // Ring fill AFTER W-stage loads (so in-loop vmcnt counts are exact: the
    // only outstanding VMEM at the barrier is these 12 asm loads).
    LOAD_A(rA, 0);
    LOAD_A(rB, 1);
    LOAD_A(rC, 2);

    f32x4 acc[2][8];
    #pragma unroll
    for (int mi = 0; mi < 2; ++mi)
        #pragma unroll
        for (int ni = 0; ni < 8; ++ni) {
            acc[mi][ni][0] = 0.f; acc[mi][ni][1] = 0.f;
            acc[mi][ni][2] = 0.f; acc[mi][ni][3] = 0.f;
        }

    __syncthreads();   // the ONLY barrier: W fully staged

    // Free-running main: 9 s-steps (18 ksteps), ring-3, counted waits.
    // In-flight: 12 -> WAITA(8) retires exactly the oldest slot.
    WAITA(8); CK(0,  rA); CK(1,  rA); LOAD_A(rA, 3);
    WAITA(8); CK(2,  rB); CK(3,  rB); LOAD_A(rB, 4);
    WAITA(8); CK(4,  rC); CK(5,  rC); LOAD_A(rC, 5);
    WAITA(8); CK(6,  rA); CK(7,  rA); LOAD_A(rA, 6);
    WAITA(8); CK(8,  rB); CK(9,  rB); LOAD_A(rB, 7);
    WAITA(8); CK(10, rC); CK(11, rC); LOAD_A(rC, 8);
    WAITA(8); CK(12, rA); CK(13, rA);
    WAITA(4); CK(14, rB); CK(15, rB);
    WAITA(0); CK(16, rC); CK(17, rC);

    #undef LOAD_A
    #undef WAITA
    #undef CK

    // Epilogue: bias + fast ELU + row-mask + NT stores.
    // C/D: col = ni*16 + (l&15), row = (l>>4)*4 + j per frag.
    float bs[8];
    #pragma unroll
    for (int ni = 0; ni < 8; ++ni) bs[ni] = bias[ni * 16 + r15];

    #pragma unroll
    for (int mi = 0; mi < 2; ++mi) {
        #pragma unroll
        for (int j = 0; j < 4; ++j) {
            const int m = wrow0 + mi * 16 + kc * 4 + j;
            if (m < M_TOT) {
                const bool z = ((m % N_) == (N_ - 1));
                float* orow = out + (size_t)m * OUT_ + r15;
                #pragma unroll
                for (int ni = 0; ni < 8; ++ni) {
                    float v = acc[mi][ni][j] + bs[ni];
                    const float e = __expf(v) - 1.0f;   // fast ELU
                    v = v > 0.f ? v : e;
                    if (z) v = 0.f;
                    __builtin_nontemporal_store(v, &orow[ni * 16]);
                }
            }
        }
    }
}

extern "C" void kernel_launch(void* const* d_in, const int* in_sizes, int n_in,
                              void* d_out, int out_size, void* d_ws, size_t ws_size,
                              hipStream_t stream) {
    const float* x    = (const float*)d_in[0];
    const void*  adj  = d_in[1];
    const float* W    = (const float*)d_in[2];
    const float* bias = (const float*)d_in[3];
    float* out        = (float*)d_out;

    char* ws = (char*)d_ws;
    unsigned short* xb = (unsigned short*)(ws + WS_XB);
    unsigned short* Wb = (unsigned short*)(ws + WS_WB);

    const int nx8 = X_ELEMS / 8;          // 1,285,888
    const int nw8 = (OUT_ * K_) / 8;      // 9,216
    cvt_xw<<<(nx8 + nw8 + 255) / 256, 256, 0, stream>>>(x, W, xb, Wb, nx8, nw8);

    const int grid = (M_TOT + 255) / 256; // 628 = 8*78 + 4
    spiral_mfma<<<grid, 512, 0, stream>>>(xb, adj, Wb, bias, out);
}

// Round 12
// 57.531 us; speedup vs baseline: 1.1742x; 1.1742x over previous
//
#include <hip/hip_runtime.h>
#include <cstdint>
#include <cstddef>

// Problem constants
#define B_    32
#define N_    5023
#define F_    64
#define S_    9
#define OUT_  128
#define M_TOT (B_ * N_)        // 160736
#define K_    (S_ * F_)        // 576

// Workspace layout (bytes)
#define X_ELEMS   (B_ * N_ * F_)          // 10,287,104
#define WS_XB     0                        // bf16 x: 20,574,208 B
#define WS_WB     20574208                 // bf16 W: 147,456 B

typedef __attribute__((ext_vector_type(8))) short          bf16x8;
typedef __attribute__((ext_vector_type(4))) float          f32x4;
typedef __attribute__((ext_vector_type(8))) unsigned short u16x8;

// ---------------------------------------------------------------------------
// Fused fp32->bf16 (RNE) conversion for x and W in one grid.
// ---------------------------------------------------------------------------
__global__ void cvt_xw(const float* __restrict__ x, const float* __restrict__ W,
                       unsigned short* __restrict__ xb, unsigned short* __restrict__ Wb,
                       int nx8, int nw8) {
    const int i = blockIdx.x * blockDim.x + threadIdx.x;
    const float* src;
    unsigned short* dst;
    if (i < nx8) { src = x + (size_t)i * 8; dst = xb + (size_t)i * 8; }
    else {
        const int j = i - nx8;
        if (j >= nw8) return;
        src = W + (size_t)j * 8; dst = Wb + (size_t)j * 8;
    }
    const float4 v0 = ((const float4*)src)[0], v1 = ((const float4*)src)[1];
    const float vv[8] = {v0.x, v0.y, v0.z, v0.w, v1.x, v1.y, v1.z, v1.w};
    u16x8 r;
    #pragma unroll
    for (int k = 0; k < 8; ++k) {
        uint32_t u = __float_as_uint(vv[k]);
        u = u + 0x7fffu + ((u >> 16) & 1u);
        r[k] = (unsigned short)(u >> 16);
    }
    *(u16x8*)dst = r;
}

// ---------------------------------------------------------------------------
// Round-12 main kernel: 128 rows x 128 cols per block, 4 waves (2x2), wave
// tile 64x64 (4mi x 4ni frags of mfma_f32_16x16x32_bf16) -> ds_read/MFMA
// = 0.5 (8 b128 reads per 16 MFMA), half of r10.
//
// K-step = 32 (18 steps). LDS: 3 x {A[128][32], W[128][32]} = 48 KB ->
// 3 blocks/CU (12 waves). TRUE counted-vmcnt pipeline (T3/T4):
//   step t: s_waitcnt vmcnt(4)            // retire stage(t), issued @ t-2
//           __builtin_amdgcn_s_barrier()  // RAW barrier - __syncthreads()
//                                         // would emit vmcnt(0) and collapse
//                                         // the pipeline (r9==r10 post-mortem)
//           COMPUTE(t%3)
//           STAGE((t+2)%3, t+2)           // 4 global_load_lds per wave
// Safety: own-wave vmcnt before own barrier => all waves' stage(t) done
// after barrier(t); compute(t-1) ds_reads are lgkm-retired before their
// MFMAs, so stage(t+2)'s overwrite of buffer (t+2)%3 == (t-1)%3 is ordered
// by barrier(t). Swizzle: r10's measured-0-conflict scheme (64-B rows,
// phys16Bchunk = logical ^ ((row>>1)&3), src-preswizzled, dest linear).
// ---------------------------------------------------------------------------
__global__ __launch_bounds__(256, 3)
void spiral_mfma(const unsigned short* __restrict__ xb,
                 const void* __restrict__ adj,
                 const unsigned short* __restrict__ Wb,
                 const float* __restrict__ bias,
                 float* __restrict__ out) {
    __shared__ unsigned short Alds[3][128 * 32];   // 24 KB
    __shared__ unsigned short Wlds[3][128 * 32];   // 24 KB

    const int tid = threadIdx.x;
    const int l   = tid & 63;
    const int w   = tid >> 6;                      // 0..3
    const int wr  = w >> 1;                        // row half 0..1
    const int wc  = w & 1;                         // col half 0..1
    const int r15 = l & 15;

    // Uniform dtype probe: odd 32-bit words of the first 8 int64 slots are
    // all zero iff adj is int64. Scalar loads, broadcast.
    const int* aw = (const int*)adj;
    const int pv = aw[1] | aw[3] | aw[5] | aw[7] | aw[9] | aw[11] | aw[13] | aw[15];
    const int sh = (pv == 0) ? 3 : 2;              // byte shift per element
    const char* adjp = (const char*)adj;

    // XCD-chunked bijective swizzle: 1256 = 8 * 157.
    const int bid = blockIdx.x;
    const int nb  = (bid & 7) * 157 + (bid >> 3);
    const int m0  = nb * 128;

    // Staging: wave w covers rows [w*32, w*32+32), 2 issues of 16 rows;
    // lane l -> row +(l>>2), dest chunk (l&3). Pre-swizzled source chunk:
    // lc = (l&3) ^ ((l>>3)&3)  (involution of phys = logical ^ ((row>>1)&3)).
    const int lc8 = ((l & 3) ^ ((l >> 3) & 3)) * 8;

    uint32_t xrb[2];
    int      idxv[2][S_];
    #pragma unroll
    for (int i = 0; i < 2; ++i) {
        int r = m0 + w * 32 + i * 16 + (l >> 2);
        if (r >= M_TOT) r = M_TOT - 1;
        xrb[i] = (uint32_t)(r / N_) * (N_ * F_);
        const int base = r * S_;
        #pragma unroll
        for (int s = 0; s < S_; ++s)
            idxv[i][s] = *(const int*)(adjp + ((size_t)(base + s) << sh));
    }
    // W staging rows (no gather): wrow_i = w*32 + i*16 + (l>>2)
    const int wsr = w * 32 + (l >> 2);

    #define STAGE(buf_, t_)                                                     \
        do {                                                                    \
            const int s_ = (t_) >> 1, hf_ = ((t_) & 1) * 32;                    \
            _Pragma("unroll")                                                   \
            for (int i_ = 0; i_ < 2; ++i_) {                                    \
                const unsigned short* srcA = xb + xrb[i_] +                     \
                    (uint32_t)idxv[i_][s_] * 64u + hf_ + lc8;                   \
                __builtin_amdgcn_global_load_lds(                               \
                    (const __attribute__((address_space(1))) void*)srcA,        \
                    (__attribute__((address_space(3))) void*)                   \
                        &Alds[(buf_)][(w * 32 + i_ * 16) * 32], 16, 0, 0);      \
                const unsigned short* srcW = Wb +                               \
                    (size_t)(wsr + i_ * 16) * K_ + (t_) * 32 + lc8;             \
                __builtin_amdgcn_global_load_lds(                               \
                    (const __attribute__((address_space(1))) void*)srcW,        \
                    (__attribute__((address_space(3))) void*)                   \
                        &Wlds[(buf_)][(w * 32 + i_ * 16) * 32], 16, 0, 0);      \
            }                                                                   \
        } while (0)

    #define WAITV(N_)                                                           \
        do {                                                                    \
            asm volatile("s_waitcnt vmcnt(" #N_ ")" ::: "memory");              \
            __builtin_amdgcn_sched_barrier(0);                                  \
        } while (0)

    #define BAR                                                                 \
        do {                                                                    \
            __builtin_amdgcn_s_barrier();                                       \
            __builtin_amdgcn_sched_barrier(0);                                  \
        } while (0)

    // Reader phys chunk offset (elements), constant per lane:
    const int ph8 = ((l >> 4) ^ ((l >> 1) & 3)) * 8;

    #define COMPUTE(buf_)                                                       \
        do {                                                                    \
            bf16x8 av[4], bv[4];                                                \
            _Pragma("unroll")                                                   \
            for (int mi = 0; mi < 4; ++mi)                                      \
                av[mi] = *(const bf16x8*)                                       \
                    &Alds[(buf_)][(wr * 64 + mi * 16 + r15) * 32 + ph8];        \
            _Pragma("unroll")                                                   \
            for (int ni = 0; ni < 4; ++ni)                                      \
                bv[ni] = *(const bf16x8*)                                       \
                    &Wlds[(buf_)][(wc * 64 + ni * 16 + r15) * 32 + ph8];        \
            __builtin_amdgcn_s_setprio(1);                                      \
            _Pragma("unroll")                                                   \
            for (int mi = 0; mi < 4; ++mi)                                      \
                _Pragma("unroll")                                               \
                for (int ni = 0; ni < 4; ++ni)                                  \
                    acc[mi][ni] = __builtin_amdgcn_mfma_f32_16x16x32_bf16(      \
                        av[mi], bv[ni], acc[mi][ni], 0, 0, 0);                  \
            __builtin_amdgcn_s_setprio(0);                                      \
        } while (0)

    f32x4 acc[4][4];
    #pragma unroll
    for (int mi = 0; mi < 4; ++mi)
        #pragma unroll
        for (int ni = 0; ni < 4; ++ni) {
            acc[mi][ni][0] = 0.f; acc[mi][ni][1] = 0.f;
            acc[mi][ni][2] = 0.f; acc[mi][ni][3] = 0.f;
        }

    // Drain idx loads so in-loop vmcnt counts are exact.
    __builtin_amdgcn_sched_barrier(0);
    asm volatile("s_waitcnt vmcnt(0)" ::: "memory");
    __builtin_amdgcn_sched_barrier(0);

    STAGE(0, 0);
    STAGE(1, 1);
    // in-flight: 8 (4 per stage per wave)

    // 18 steps; vmcnt(4) retires the stage issued two steps earlier.
    WAITV(4); BAR; COMPUTE(0); STAGE(2, 2);
    WAITV(4); BAR; COMPUTE(1); STAGE(0, 3);
    WAITV(4); BAR; COMPUTE(2); STAGE(1, 4);
    WAITV(4); BAR; COMPUTE(0); STAGE(2, 5);
    WAITV(4); BAR; COMPUTE(1); STAGE(0, 6);
    WAITV(4); BAR; COMPUTE(2); STAGE(1, 7);
    WAITV(4); BAR; COMPUTE(0); STAGE(2, 8);
    WAITV(4); BAR; COMPUTE(1); STAGE(0, 9);
    WAITV(4); BAR; COMPUTE(2); STAGE(1, 10);
    WAITV(4); BAR; COMPUTE(0); STAGE(2, 11);
    WAITV(4); BAR; COMPUTE(1); STAGE(0, 12);
    WAITV(4); BAR; COMPUTE(2); STAGE(1, 13);
    WAITV(4); BAR; COMPUTE(0); STAGE(2, 14);
    WAITV(4); BAR; COMPUTE(1); STAGE(0, 15);
    WAITV(4); BAR; COMPUTE(2); STAGE(1, 16);
    WAITV(4); BAR; COMPUTE(0); STAGE(2, 17);
    WAITV(4); BAR; COMPUTE(1);
    WAITV(0); BAR; COMPUTE(2);

    #undef STAGE
    #undef WAITV
    #undef BAR
    #undef COMPUTE

    // Epilogue: bias + fast ELU + row-mask + NT stores.
    // C/D: col = l&15, row = (l>>4)*4 + j per 16x16 frag.
    float bs[4];
    #pragma unroll
    for (int ni = 0; ni < 4; ++ni) bs[ni] = bias[wc * 64 + ni * 16 + r15];

    const int rb = m0 + wr * 64 + (l >> 4) * 4;
    const int cb = wc * 64 + r15;
    #pragma unroll
    for (int mi = 0; mi < 4; ++mi) {
        #pragma unroll
        for (int j = 0; j < 4; ++j) {
            const int m = rb + mi * 16 + j;
            if (m < M_TOT) {
                const bool z = ((m % N_) == (N_ - 1));
                float* orow = out + (size_t)m * OUT_ + cb;
                #pragma unroll
                for (int ni = 0; ni < 4; ++ni) {
                    float v = acc[mi][ni][j] + bs[ni];
                    const float e = __expf(v) - 1.0f;   // fast ELU
                    v = v > 0.f ? v : e;
                    if (z) v = 0.f;
                    __builtin_nontemporal_store(v, &orow[ni * 16]);
                }
            }
        }
    }
}

extern "C" void kernel_launch(void* const* d_in, const int* in_sizes, int n_in,
                              void* d_out, int out_size, void* d_ws, size_t ws_size,
                              hipStream_t stream) {
    const float* x    = (const float*)d_in[0];
    const void*  adj  = d_in[1];
    const float* W    = (const float*)d_in[2];
    const float* bias = (const float*)d_in[3];
    float* out        = (float*)d_out;

    char* ws = (char*)d_ws;
    unsigned short* xb = (unsigned short*)(ws + WS_XB);
    unsigned short* Wb = (unsigned short*)(ws + WS_WB);

    const int nx8 = X_ELEMS / 8;          // 1,285,888
    const int nw8 = (OUT_ * K_) / 8;      // 9,216
    cvt_xw<<<(nx8 + nw8 + 255) / 256, 256, 0, stream>>>(x, W, xb, Wb, nx8, nw8);

    const int grid = (M_TOT + 127) / 128; // 1256 = 8 * 157
    spiral_mfma<<<grid, 256, 0, stream>>>(xb, adj, Wb, bias, out);
}